// Round 16
// baseline (41.394 us; speedup 1.0000x reference)
//
#include <hip/hip_runtime.h>

// ConvPool r12e (5th submit; rounds 12-15 all died in infra BEFORE file push
// — "connection closed while sending first message" on container
// also-rich-neat-lion — kernel has never executed).
// Pass 2 is LDS-free streaming direct-conv.
// x(32,16,128,128) f32, weight(144,64), bias(64) -> out(32,64,63,63) f32.
// Pass 1 (r9-verified, unchanged): x -> xh fp16 [b][row][col][ch] + W frags.
// Pass 2 insight: in xh layout the MFMA B-frag IS a linear per-lane 16B
// global load (lane l: row*4096 + (pos0+(l&31))*32 + (l>>5)*16) -> perfectly
// coalesced dwordx4. So: no LDS, no barrier, no staging. Per pooled row:
// 12 frag loads (4 rows x 3 m-shifts; overlaps L1-hot, cross-block reuse
// L3-absorbed) feed 18 MFMA; epilogue pools in-lane + shfl_xor(1) and stores
// straight from registers. Blocks free-run (no phases to lockstep).
// Block = (b, strip of 4 pooled rows, o-half): W[9] = 36 VGPR, 16 waves/CU.

typedef _Float16 f16x8 __attribute__((ext_vector_type(8)));
typedef float f32x16 __attribute__((ext_vector_type(16)));

#define MFMA16(A, B, C) __builtin_amdgcn_mfma_f32_32x32x16_f16(A, B, C, 0, 0, 0)
#define XH_BYTES 16777216  // 32*128*128*2 granules * 16 B = 16 MiB

// blocks [0,4096): xh granule g = (b,row,col,hf): 8 ch fp16 at xh + g*16,
//   value[j] = f16(x[b][hf*8+j][row][col]).
// blocks [4096,4101): W frags (r7-r11-verified layout):
//   ws + XH + (t*2+ot)*1024 + (hf*32+(o&31))*16 + j*2
//   = f16(weight[((hf*8+j)*9+t)*64 + o])
__global__ void convert_xw(const float* __restrict__ x,
                           const float* __restrict__ weight,
                           char* __restrict__ ws) {
  const int n = blockIdx.x;
  if (n < 4096) {
    const int g = n * 256 + threadIdx.x;
    const int hf = g & 1, col = (g >> 1) & 127, row = (g >> 8) & 127, b = g >> 15;
    _Float16 h[8];
#pragma unroll
    for (int j = 0; j < 8; ++j)
      h[j] = (_Float16)x[((b * 16 + hf * 8 + j) * 128 + row) * 128 + col];
    *(f16x8*)(ws + g * 16) = *(f16x8*)h;
  } else {
    const int tau = (n - 4096) * 256 + threadIdx.x;
    if (tau >= 1152) return;  // 9 taps x 64 o x 2 k-halves
    const int t = tau >> 7, r = tau & 127, o = r >> 1, hf = r & 1;
    _Float16 h[8];
#pragma unroll
    for (int j = 0; j < 8; ++j)
      h[j] = (_Float16)weight[((hf * 8 + j) * 9 + t) * 64 + o];
    const int off = (t * 2 + (o >> 5)) * 1024 + (hf * 32 + (o & 31)) * 16;
    *(f16x8*)(ws + XH_BYTES + off) = *(f16x8*)h;
  }
}

// No LDS. Reads may bleed <=48B past a row/batch end (pos+m up to 129):
// lands in the next row / W-frag region (valid memory), feeds only pooled
// col 63 which pw<63 discards.
__global__ __launch_bounds__(256, 4)
void convpool_main(const char* __restrict__ ws, const float* __restrict__ bias,
                   float* __restrict__ out) {
  const int bx = blockIdx.x;           // sg*2 + oh
  const int sg = bx >> 1;              // strip: pooled rows 4sg..4sg+nsteps-1
  const int oh = bx & 1;               // o-tile: o in [oh*32, oh*32+32)
  const int b = blockIdx.y;
  const int nsteps = (sg < 15) ? 4 : 3;  // 63 = 15*4 + 3
  const int lane = threadIdx.x & 63;
  const int ph = threadIdx.x >> 6;     // wave -> positions [ph*32, ph*32+32)
  const int half = lane >> 5;          // k-half (ch 0-7 / 8-15)
  const int c31 = lane & 31;

  // ---- this o-half's W frags -> registers (36 VGPR, L2-resident) ----
  const char* wsW = ws + XH_BYTES;
  f16x8 W[9];
#pragma unroll
  for (int t = 0; t < 9; ++t)
    W[t] = *(const f16x8*)(wsW + (t * 2 + oh) * 1024 + lane * 16);

  // per-lane byte offset within a row of xh
  const char* xbb = ws + (size_t)b * 524288;  // batch base (128 rows * 4096 B)
  const int lofs = (ph * 32 + c31) * 32 + half * 16;

  const int pw = ph * 16 + (c31 >> 1);
  const bool doit = ((c31 & 1) == 0) && (pw < 63);

  for (int i = 0; i < nsteps; ++i) {
    const int p = 4 * sg + i;
    const char* rbase = xbb + (size_t)(2 * p) * 4096 + lofs;

    // ---- 12 direct frag loads: rows 2p..2p+3 x m-shifts 0..2 ----
    f16x8 X[4][3];
#pragma unroll
    for (int r = 0; r < 4; ++r)
#pragma unroll
      for (int m = 0; m < 3; ++m)
        X[r][m] = *(const f16x8*)(rbase + r * 4096 + m * 32);

    f32x16 a0, a1;  // conv row 2p / 2p+1 accumulators
#pragma unroll
    for (int q = 0; q < 16; ++q) { a0[q] = 0.f; a1[q] = 0.f; }
    __builtin_amdgcn_s_setprio(1);
#pragma unroll
    for (int t = 0; t < 9; ++t) {
      const int n = t / 3, m = t - 3 * n;
      a0 = MFMA16(W[t], X[n][m], a0);
      a1 = MFMA16(W[t], X[n + 1][m], a1);
    }
    __builtin_amdgcn_s_setprio(0);

    // ---- pool + bias + relu + direct store (r7-r11-verified mapping) ----
    const int obase = ((b * 64) * 63 + p) * 63 + pw;  // + o*3969
#pragma unroll
    for (int q = 0; q < 16; ++q) {
      const int o0 = oh * 32 + (q & 3) + 8 * (q >> 2);  // o = o0 + 4*half
      float v = fmaxf(a0[q], a1[q]);                    // pool conv rows
      v = fmaxf(v, __shfl_xor(v, 1, 64));               // pool col pair
      const float bv = half ? bias[o0 + 4] : bias[o0];
      v = fmaxf(v + bv, 0.0f);
      if (doit) out[obase + (o0 + 4 * half) * 3969] = v;
    }
  }
}

extern "C" void kernel_launch(void* const* d_in, const int* in_sizes, int n_in,
                              void* d_out, int out_size, void* d_ws, size_t ws_size,
                              hipStream_t stream) {
  const float* x = (const float*)d_in[0];
  const float* wgt = (const float*)d_in[1];
  const float* bias = (const float*)d_in[2];
  float* out = (float*)d_out;
  char* ws = (char*)d_ws;  // uses 16 MiB (xh) + 18 KiB (W frags)
  convert_xw<<<dim3(4101), 256, 0, stream>>>(x, wgt, ws);
  convpool_main<<<dim3(32, 32), 256, 0, stream>>>(ws, bias, out);
}